// Round 1
// baseline (257.445 us; speedup 1.0000x reference)
//
#include <hip/hip_runtime.h>
#include <hip/hip_bf16.h>
#include <math.h>

#define N_NODES 4096
#define D 128
#define NPB 16          // nodes per block in GEMM kernels
#define GAT_N 64        // nodes in graph 0 (only graph whose GAT output is used)
#define HEADS 3

__device__ __forceinline__ float leaky01(float v) { return v >= 0.f ? v : 0.01f * v; }

// ---------------- CSR build ----------------
__global__ void k_zero_i(int* p, int n) {
    int i = blockIdx.x * blockDim.x + threadIdx.x;
    if (i < n) p[i] = 0;
}
__global__ void k_zero_f(float* p, int n) {
    int i = blockIdx.x * blockDim.x + threadIdx.x;
    if (i < n) p[i] = 0.f;
}
__global__ void k_count(const int* __restrict__ dst, int E, int* __restrict__ counts) {
    int e = blockIdx.x * blockDim.x + threadIdx.x;
    if (e < E) atomicAdd(&counts[dst[e]], 1);
}
// single block, 1024 threads, 4096 counts -> offsets[4097] and cursor copy
__global__ void k_scan(const int* __restrict__ counts, int* __restrict__ offsets,
                       int* __restrict__ cursor) {
    __shared__ int part[1024];
    int t = threadIdx.x;
    int base = t * 4;
    int c0 = counts[base], c1 = counts[base + 1], c2 = counts[base + 2], c3 = counts[base + 3];
    int s = c0 + c1 + c2 + c3;
    part[t] = s;
    __syncthreads();
    for (int off = 1; off < 1024; off <<= 1) {
        int v = (t >= off) ? part[t - off] : 0;
        __syncthreads();
        part[t] += v;
        __syncthreads();
    }
    int excl = part[t] - s;  // exclusive prefix of this thread's 4-chunk
    int o0 = excl, o1 = excl + c0, o2 = excl + c0 + c1, o3 = excl + c0 + c1 + c2;
    offsets[base] = o0; offsets[base + 1] = o1; offsets[base + 2] = o2; offsets[base + 3] = o3;
    cursor[base] = o0;  cursor[base + 1] = o1;  cursor[base + 2] = o2;  cursor[base + 3] = o3;
    if (t == 1023) offsets[4096] = excl + s;
}
__global__ void k_scatter(const int* __restrict__ src, const int* __restrict__ dst, int E,
                          int* __restrict__ cursor, int* __restrict__ csr_src) {
    int e = blockIdx.x * blockDim.x + threadIdx.x;
    if (e < E) {
        int p = atomicAdd(&cursor[dst[e]], 1);
        csr_src[p] = src[e];
    }
}

// ---------------- graphnet ----------------
// h = leaky(x @ Wm + bm)   [N,128] = [N,128]@[128,128]
__global__ __launch_bounds__(256) void k_node_mm(const float* __restrict__ x,
                                                 const float* __restrict__ W,
                                                 const float* __restrict__ b,
                                                 float* __restrict__ out) {
    __shared__ float xs[NPB][D];
    int tid = threadIdx.x;
    int n0 = blockIdx.x * NPB;
    for (int i = tid; i < NPB * D; i += 256)
        xs[i / D][i % D] = x[(n0 + i / D) * D + (i % D)];
    __syncthreads();
    int col = tid & 127;
    int half = tid >> 7;  // 0/1 -> nodes [half*8, half*8+8)
    float acc[8] = {0.f, 0.f, 0.f, 0.f, 0.f, 0.f, 0.f, 0.f};
    for (int k = 0; k < D; k++) {
        float w = W[k * D + col];
#pragma unroll
        for (int nn = 0; nn < 8; nn++) acc[nn] += xs[half * 8 + nn][k] * w;
    }
    float bb = b[col];
#pragma unroll
    for (int nn = 0; nn < 8; nn++) {
        float v = acc[nn] + bb;
        out[(n0 + half * 8 + nn) * D + col] = leaky01(v);
    }
}

// agg[n][j] = max over incoming edges of h[src][j], empty -> 0
__global__ __launch_bounds__(128) void k_segmax(const float* __restrict__ h,
                                                const int* __restrict__ offsets,
                                                const int* __restrict__ csr_src,
                                                float* __restrict__ agg) {
    int n = blockIdx.x;
    int j = threadIdx.x;
    int s = offsets[n], e = offsets[n + 1];
    float m = -INFINITY;
    for (int p = s; p < e; p++) {
        int sn = csr_src[p];
        m = fmaxf(m, h[sn * D + j]);
    }
    agg[n * D + j] = (e > s) ? m : 0.f;
}

// x_next = leaky([x, xg, agg] @ Wa + ba) + x
__global__ __launch_bounds__(256) void k_update(const float* __restrict__ x,
                                                const float* __restrict__ x_att,
                                                const int* __restrict__ batch_ind,
                                                const float* __restrict__ agg,
                                                const float* __restrict__ Wa,
                                                const float* __restrict__ ba,
                                                float* __restrict__ out) {
    __shared__ float zs[NPB][3 * D];
    int tid = threadIdx.x;
    int n0 = blockIdx.x * NPB;
    for (int i = tid; i < NPB * D; i += 256) {
        int n = i / D, k = i % D;
        int gn = n0 + n;
        zs[n][k]         = x[gn * D + k];
        zs[n][D + k]     = x_att[batch_ind[gn] * D + k];
        zs[n][2 * D + k] = agg[gn * D + k];
    }
    __syncthreads();
    int col = tid & 127;
    int half = tid >> 7;
    float acc[8] = {0.f, 0.f, 0.f, 0.f, 0.f, 0.f, 0.f, 0.f};
    for (int k = 0; k < 3 * D; k++) {
        float w = Wa[k * D + col];
#pragma unroll
        for (int nn = 0; nn < 8; nn++) acc[nn] += zs[half * 8 + nn][k] * w;
    }
    float bb = ba[col];
#pragma unroll
    for (int nn = 0; nn < 8; nn++) {
        float v = leaky01(acc[nn] + bb);
        out[(n0 + half * 8 + nn) * D + col] = v + zs[half * 8 + nn][col];
    }
}

// ---------------- GATv2 on graph 0 only ----------------
// xl/xr[n][c] = x[n] @ W[:,c] + b[c], n in [0,64), c in [0,384)
__global__ __launch_bounds__(384) void k_gat_xlxr(const float* __restrict__ x,
                                                  const float* __restrict__ Wl,
                                                  const float* __restrict__ bl,
                                                  const float* __restrict__ Wr,
                                                  const float* __restrict__ br,
                                                  float* __restrict__ xl,
                                                  float* __restrict__ xr) {
    __shared__ float xs[D];
    int n = blockIdx.x, t = threadIdx.x;
    if (t < D) xs[t] = x[n * D + t];
    __syncthreads();
    float al = 0.f, ar = 0.f;
    for (int k = 0; k < D; k++) {
        float xv = xs[k];
        al += xv * Wl[k * 384 + t];
        ar += xv * Wr[k * 384 + t];
    }
    xl[n * 384 + t] = al + bl[t];
    xr[n * 384 + t] = ar + br[t];
}

// per (d, head): logits over all 64 sources, softmax, weighted sum of xl
__global__ __launch_bounds__(64) void k_gat_attn(const float* __restrict__ xl,
                                                 const float* __restrict__ xr,
                                                 const float* __restrict__ att,
                                                 float* __restrict__ outh) {
    int d = blockIdx.x;
    int hh = blockIdx.y;
    int t = threadIdx.x;  // 64 threads (one wave)
    __shared__ float xr_d[D];
    __shared__ float attv[D];
    __shared__ float alpha[GAT_N];
    xr_d[t]      = xr[d * 384 + hh * D + t];
    xr_d[t + 64] = xr[d * 384 + hh * D + t + 64];
    attv[t]      = att[hh * D + t];
    attv[t + 64] = att[hh * D + t + 64];
    __syncthreads();
    // thread t computes logit for source s = t
    float lg = 0.f;
    const float* xls = &xl[t * 384 + hh * D];
    for (int k = 0; k < D; k++) {
        float e = xls[k] + xr_d[k];
        e = e >= 0.f ? e : 0.2f * e;
        lg += e * attv[k];
    }
    float mx = lg;
#pragma unroll
    for (int o = 32; o > 0; o >>= 1) mx = fmaxf(mx, __shfl_xor(mx, o));
    float a = expf(lg - mx);
    float sum = a;
#pragma unroll
    for (int o = 32; o > 0; o >>= 1) sum += __shfl_xor(sum, o);
    alpha[t] = a / sum;
    __syncthreads();
    float o0 = 0.f, o1 = 0.f;
    for (int s = 0; s < GAT_N; s++) {
        float al = alpha[s];
        o0 += al * xl[s * 384 + hh * D + t];
        o1 += al * xl[s * 384 + hh * D + t + 64];
    }
    outh[(hh * GAT_N + d) * D + t] = o0;
    outh[(hh * GAT_N + d) * D + t + 64] = o1;
}

// x_att[n][k] = leaky(mean_h outh + bias[k])
__global__ void k_gat_final(const float* __restrict__ outh, const float* __restrict__ bias,
                            float* __restrict__ x_att) {
    int i = blockIdx.x * blockDim.x + threadIdx.x;
    if (i < GAT_N * D) {
        int k = i & 127;
        float v = (outh[i] + outh[GAT_N * D + i] + outh[2 * GAT_N * D + i]) * (1.f / 3.f) + bias[k];
        x_att[i] = leaky01(v);
    }
}

extern "C" void kernel_launch(void* const* d_in, const int* in_sizes, int n_in,
                              void* d_out, int out_size, void* d_ws, size_t ws_size,
                              hipStream_t stream) {
    (void)n_in; (void)out_size; (void)ws_size;
    const float* x_in      = (const float*)d_in[0];
    const int*   edge_idx  = (const int*)d_in[1];   // [2][E]
    const int*   batch_ind = (const int*)d_in[2];
    // d_in[3] edge_complete: structurally known (complete within 64-node graphs) -> unused
    const float* Wm  = (const float*)d_in[4];
    const float* bm  = (const float*)d_in[5];
    const float* Wa  = (const float*)d_in[6];
    const float* ba  = (const float*)d_in[7];
    const float* Wl  = (const float*)d_in[8];
    const float* bl  = (const float*)d_in[9];
    const float* Wr  = (const float*)d_in[10];
    const float* br  = (const float*)d_in[11];
    const float* att_w    = (const float*)d_in[12];
    const float* att_bias = (const float*)d_in[13];
    const int E = in_sizes[1] / 2;
    const int* e_src = edge_idx;
    const int* e_dst = edge_idx + E;

    // ---- workspace layout ----
    char* ws = (char*)d_ws;
    size_t off = 0;
    auto alloc = [&](size_t bytes) { void* p = ws + off; off += (bytes + 255) & ~size_t(255); return p; };
    float* h      = (float*)alloc(N_NODES * D * sizeof(float));
    float* agg    = (float*)alloc(N_NODES * D * sizeof(float));
    float* xbuf0  = (float*)alloc(N_NODES * D * sizeof(float));
    float* xbuf1  = (float*)alloc(N_NODES * D * sizeof(float));
    float* x_att  = (float*)alloc(GAT_N * D * sizeof(float));
    float* xl     = (float*)alloc(GAT_N * 384 * sizeof(float));
    float* xr     = (float*)alloc(GAT_N * 384 * sizeof(float));
    float* outh   = (float*)alloc(HEADS * GAT_N * D * sizeof(float));
    int* counts   = (int*)alloc(N_NODES * sizeof(int));
    int* offsets  = (int*)alloc((N_NODES + 1) * sizeof(int));
    int* cursor   = (int*)alloc(N_NODES * sizeof(int));
    int* csr_src  = (int*)alloc(E * sizeof(int));

    // ---- CSR build (edges constant across steps) ----
    k_zero_i<<<(N_NODES + 255) / 256, 256, 0, stream>>>(counts, N_NODES);
    k_count<<<(E + 255) / 256, 256, 0, stream>>>(e_dst, E, counts);
    k_scan<<<1, 1024, 0, stream>>>(counts, offsets, cursor);
    k_scatter<<<(E + 255) / 256, 256, 0, stream>>>(e_src, e_dst, E, cursor, csr_src);
    // x_att starts as zeros
    k_zero_f<<<(GAT_N * D + 255) / 256, 256, 0, stream>>>(x_att, GAT_N * D);

    const float* xc = x_in;
    for (int i = 0; i < 4; i++) {
        k_node_mm<<<N_NODES / NPB, 256, 0, stream>>>(xc, Wm + (size_t)i * D * D, bm + (size_t)i * D, h);
        k_segmax<<<N_NODES, 128, 0, stream>>>(h, offsets, csr_src, agg);
        float* xn = (i == 3) ? (float*)d_out : ((i & 1) ? xbuf1 : xbuf0);
        k_update<<<N_NODES / NPB, 256, 0, stream>>>(xc, x_att, batch_ind, agg,
                                                    Wa + (size_t)i * 3 * D * D, ba + (size_t)i * D, xn);
        if (i < 3) {
            k_gat_xlxr<<<GAT_N, 384, 0, stream>>>(xn, Wl + (size_t)i * D * 384, bl + (size_t)i * 384,
                                                  Wr + (size_t)i * D * 384, br + (size_t)i * 384, xl, xr);
            dim3 g2(GAT_N, HEADS);
            k_gat_attn<<<g2, 64, 0, stream>>>(xl, xr, att_w + (size_t)i * HEADS * D, outh);
            k_gat_final<<<(GAT_N * D + 255) / 256, 256, 0, stream>>>(outh, att_bias + (size_t)i * D, x_att);
        }
        xc = xn;
    }
}